// Round 8
// baseline (3034.145 us; speedup 1.0000x reference)
//
#include <hip/hip_runtime.h>
#include <math.h>

#define TT 1024
#define DD 1024
#define HH 16
#define KVHN 4
#define HDW 64
#define DFFN 4096
#define WIN 256

// ---------- guard: zero output ----------
__global__ void zero_k(float* out, int n){
  for (int i = blockIdx.x * blockDim.x + threadIdx.x; i < n; i += gridDim.x * blockDim.x)
    out[i] = 0.f;
}

// ---------- fp32 layernorm, LDS-tree reduction ----------
__global__ __launch_bounds__(256) void ln32_k(const float* __restrict__ x,
                                              const float* __restrict__ g,
                                              const float* __restrict__ b,
                                              float* __restrict__ out){
  __shared__ float red[256];
  int row = blockIdx.x, tid = threadIdx.x;
  const float* xr = x + (size_t)row * DD;
  float4 v = *(const float4*)(xr + tid * 4);
  red[tid] = v.x + v.y + v.z + v.w;
  __syncthreads();
  for (int s = 128; s > 0; s >>= 1){
    if (tid < s) red[tid] += red[tid + s];
    __syncthreads();
  }
  float mu = red[0] * (1.f / DD);
  __syncthreads();
  float dx = v.x - mu, dy = v.y - mu, dz = v.z - mu, dw = v.w - mu;
  red[tid] = dx*dx + dy*dy + dz*dz + dw*dw;
  __syncthreads();
  for (int s = 128; s > 0; s >>= 1){
    if (tid < s) red[tid] += red[tid + s];
    __syncthreads();
  }
  float var = red[0] * (1.f / DD);
  float inv = rsqrtf(var + 1e-5f);
  float4 gv = *(const float4*)(g + tid * 4);
  float4 bv = *(const float4*)(b + tid * 4);
  float4 ov;
  ov.x = dx * inv * gv.x + bv.x;
  ov.y = dy * inv * gv.y + bv.y;
  ov.z = dz * inv * gv.z + bv.z;
  ov.w = dw * inv * gv.w + bv.w;
  *(float4*)(out + (size_t)row * DD + tid * 4) = ov;
}

// ---------- fp32 tiled GEMM ----------
template<int EPI>
__global__ __launch_bounds__(256) void sgemm_k(const float* __restrict__ A,
                                               const float* __restrict__ W,
                                               const float* __restrict__ bias,
                                               const float* __restrict__ res,
                                               float* __restrict__ C,
                                               int M, int N, int K, int ldw, int ldc){
  __shared__ float As[16][65];
  __shared__ float Ws[16][65];
  int tid = threadIdx.x;
  int tx = tid & 15, ty = tid >> 4;
  int row0 = blockIdx.x * 64, col0 = blockIdx.y * 64;
  float acc[4][4] = {};
  for (int k0 = 0; k0 < K; k0 += 16){
    for (int e = tid; e < 1024; e += 256){
      int r = e >> 4, kk = e & 15;
      As[kk][r] = A[(size_t)(row0 + r) * K + k0 + kk];
    }
    for (int e = tid; e < 1024; e += 256){
      int kk = e >> 6, c = e & 63;
      Ws[kk][c] = W[(size_t)(k0 + kk) * ldw + col0 + c];
    }
    __syncthreads();
#pragma unroll
    for (int kk = 0; kk < 16; kk++){
      float a[4], w[4];
#pragma unroll
      for (int i = 0; i < 4; i++) a[i] = As[kk][ty*4 + i];
#pragma unroll
      for (int j = 0; j < 4; j++) w[j] = Ws[kk][tx*4 + j];
#pragma unroll
      for (int i = 0; i < 4; i++)
#pragma unroll
        for (int j = 0; j < 4; j++)
          acc[i][j] = fmaf(a[i], w[j], acc[i][j]);
    }
    __syncthreads();
  }
#pragma unroll
  for (int i = 0; i < 4; i++){
    int gr = row0 + ty*4 + i;
#pragma unroll
    for (int j = 0; j < 4; j++){
      int gc = col0 + tx*4 + j;
      float val = acc[i][j] + (bias ? bias[gc] : 0.f);
      if constexpr (EPI == 1){
        val = 0.5f * val * (1.f + erff(val * 0.70710678118f));
      }
      if constexpr (EPI == 2){
        val += res[(size_t)gr * ldc + gc];
      }
      if constexpr (EPI == 3){
        val += C[(size_t)gr * ldc + gc];
      }
      C[(size_t)gr * ldc + gc] = val;
    }
  }
}

// ---------- fp32 RoPE, halves pairing, NEGATED rotation (probe H1) ----------
// x1' = x1*c + x2*s ; x2' = x2*c - x1*s   (rotation by -t*theta)
__global__ __launch_bounds__(256) void rope32_k(float* buf, int nheads){
  int idx = blockIdx.x * 8 + (threadIdx.x >> 5);
  int d = threadIdx.x & 31;
  int t = (idx / nheads) % TT;
  float* p = buf + (size_t)idx * HDW;
  float x1 = p[d];
  float x2 = p[d + 32];
  float theta = powf(10000.f, -(float)d * (1.f / 32.f));
  float c, s;
  sincosf((float)t * theta, &c, &s);
  p[d]      = x1 * c + x2 * s;
  p[d + 32] = x2 * c - x1 * s;
}

// ---------- fp32 probe attention, windowed ----------
__global__ __launch_bounds__(64) void attn32_k(const float* __restrict__ q,
                                               const float* __restrict__ k,
                                               const float* __restrict__ v,
                                               float* __restrict__ o){
  __shared__ float qs[64], ps[64], red[64];
  int lane = threadIdx.x;
  int t = blockIdx.x, h = blockIdx.y, b = blockIdx.z;
  int kvh = h >> 2;
  qs[lane] = q[((size_t)((b*TT + t)*HH) + h) * HDW + lane];
  __syncthreads();
  int lo = t - (WIN - 1); if (lo < 0) lo = 0;
  float m = -1e30f, l = 0.f, oacc = 0.f;
  for (int c0 = (lo & ~63); c0 <= t; c0 += 64){
    int ka = c0 + lane;
    bool ok = (ka >= lo) && (ka <= t);
    float s_val = -1e30f;
    if (ok){
      const float* krow = k + ((size_t)((b*TT + ka)*KVHN) + kvh) * HDW;
      float acc = 0.f;
      for (int dd = 0; dd < 64; dd++) acc += qs[dd] * krow[dd];
      s_val = acc * 0.125f;
    }
    red[lane] = s_val; __syncthreads();
    for (int st = 32; st > 0; st >>= 1){
      if (lane < st) red[lane] = fmaxf(red[lane], red[lane + st]);
      __syncthreads();
    }
    float mx = red[0]; __syncthreads();
    float mn = fmaxf(m, mx);
    float scl = __expf(m - mn);
    float p = ok ? __expf(s_val - mn) : 0.f;
    red[lane] = p; __syncthreads();
    for (int st = 32; st > 0; st >>= 1){
      if (lane < st) red[lane] += red[lane + st];
      __syncthreads();
    }
    float ls = red[0]; __syncthreads();
    l = l * scl + ls;
    m = mn;
    ps[lane] = p; __syncthreads();
    float acc2 = 0.f;
    int cmin = (lo > c0) ? (lo - c0) : 0;
    int cmax = (t - c0 > 63) ? 63 : (t - c0);
    for (int c = cmin; c <= cmax; c++){
      const float* vrow = v + ((size_t)((b*TT + c0 + c)*KVHN) + kvh) * HDW;
      acc2 += ps[c] * vrow[lane];
    }
    oacc = oacc * scl + acc2;
    __syncthreads();
  }
  o[((size_t)((b*TT + t)*HH) + h) * HDW + lane] = oacc / l;
}

extern "C" void kernel_launch(void* const* d_in, const int* in_sizes, int n_in,
                              void* d_out, int out_size, void* d_ws, size_t ws_size,
                              hipStream_t stream){
  const float* x   = (const float*)d_in[0];
  const float* Wq  = (const float*)d_in[1];
  const float* bq  = (const float*)d_in[2];
  const float* Wk  = (const float*)d_in[3];
  const float* bk  = (const float*)d_in[4];
  const float* Wv  = (const float*)d_in[5];
  const float* bv  = (const float*)d_in[6];
  const float* Wo  = (const float*)d_in[7];
  const float* bo  = (const float*)d_in[8];
  const float* g1  = (const float*)d_in[9];
  const float* b1  = (const float*)d_in[10];
  const float* Wf1 = (const float*)d_in[11];
  const float* bf1 = (const float*)d_in[12];
  const float* Wf2 = (const float*)d_in[13];
  const float* bf2 = (const float*)d_in[14];
  const float* g2  = (const float*)d_in[15];
  const float* b2  = (const float*)d_in[16];

  static const int want[17] = {4194304, 1048576, 1024, 262144, 256, 262144, 256,
                               1048576, 1024, 1024, 1024, 4194304, 4096, 4194304,
                               1024, 1024, 1024};
  bool bad = (n_in != 17) || (out_size != 4194304) || (ws_size < (size_t)72*1024*1024);
  if (!bad) for (int i = 0; i < 17; i++) if (in_sizes[i] != want[i]) bad = true;
  if (bad){
    zero_k<<<2048, 256, 0, stream>>>((float*)d_out, out_size);
    return;
  }

  const int M = 4 * TT;
  const size_t MB = 1024 * 1024;
  char* ws = (char*)d_ws;
  float* h1  = (float*)(ws + 0*MB);
  float* qb  = (float*)(ws + 16*MB);
  float* kb  = (float*)(ws + 32*MB);
  float* vb  = (float*)(ws + 36*MB);
  float* ao  = (float*)(ws + 40*MB);
  float* x2  = (float*)(ws + 56*MB);
  float* h2  = h1;
  float* ffc = qb;
  float* out = (float*)d_out;

  // LN1
  ln32_k<<<M, 256, 0, stream>>>(x, g1, b1, h1);

  // QKV (fp32)
  sgemm_k<0><<<dim3(M/64, DD/64),  256, 0, stream>>>(h1, Wq, bq, nullptr, qb, M, DD,  DD, DD,  DD);
  sgemm_k<0><<<dim3(M/64, 256/64), 256, 0, stream>>>(h1, Wk, bk, nullptr, kb, M, 256, DD, 256, 256);
  sgemm_k<0><<<dim3(M/64, 256/64), 256, 0, stream>>>(h1, Wv, bv, nullptr, vb, M, 256, DD, 256, 256);

  // RoPE (halves pairing, NEGATED rotation — probe H1)
  rope32_k<<<(M * HH) / 8,   256, 0, stream>>>(qb, HH);
  rope32_k<<<(M * KVHN) / 8, 256, 0, stream>>>(kb, KVHN);

  // attention (windowed)
  attn32_k<<<dim3(TT, HH, 4), 64, 0, stream>>>(qb, kb, vb, ao);

  // Wo + residual -> x2
  sgemm_k<2><<<dim3(M/64, DD/64), 256, 0, stream>>>(ao, Wo, bo, x, x2, M, DD, DD, DD, DD);

  // LN2
  ln32_k<<<M, 256, 0, stream>>>(x2, g2, b2, h2);

  // FFN chunked over DFF (4 x 1024), accumulate into out
  for (int c = 0; c < 4; c++){
    int c0 = c * 1024;
    sgemm_k<1><<<dim3(M/64, 1024/64), 256, 0, stream>>>(h2, Wf1 + c0, bf1 + c0, nullptr, ffc,
                                                        M, 1024, DD, DFFN, 1024);
    if (c == 0)
      sgemm_k<2><<<dim3(M/64, DD/64), 256, 0, stream>>>(ffc, Wf2 + (size_t)c0 * DD, bf2, x2, out,
                                                        M, DD, 1024, DD, DD);
    else
      sgemm_k<3><<<dim3(M/64, DD/64), 256, 0, stream>>>(ffc, Wf2 + (size_t)c0 * DD, nullptr, nullptr, out,
                                                        M, DD, 1024, DD, DD);
  }
}

// Round 9
// 367.047 us; speedup vs baseline: 8.2664x; 8.2664x over previous
//
#include <hip/hip_runtime.h>
#include <hip/hip_bf16.h>
#include <math.h>

#define TT 1024
#define DD 1024
#define HH 16
#define KVHN 4
#define HDW 64
#define DFFN 4096
#define WIN 256

typedef __attribute__((ext_vector_type(4))) float f32x4;
typedef __attribute__((ext_vector_type(8))) __bf16 bf16x8;

__device__ inline unsigned short f2bf(float f){
  union { float f; unsigned u; } x; x.f = f;
  unsigned r = x.u + 0x7fffu + ((x.u >> 16) & 1u);
  return (unsigned short)(r >> 16);
}
__device__ inline float bf2f(unsigned short b){
  union { unsigned u; float f; } x; x.u = ((unsigned)b) << 16; return x.f;
}
__device__ inline f32x4 MFMA(bf16x8 a, bf16x8 b, f32x4 c){
  return __builtin_amdgcn_mfma_f32_16x16x32_bf16(a, b, c, 0, 0, 0);
}

__global__ void zero_k(float* out, int n){
  for (int i = blockIdx.x * blockDim.x + threadIdx.x; i < n; i += gridDim.x * blockDim.x)
    out[i] = 0.f;
}

// ---------- weight transpose: W[K][N] fp32 -> Wt[N][K] bf16 ----------
__global__ __launch_bounds__(256) void wtrans_k(const float* __restrict__ W,
                                                unsigned short* __restrict__ Wt,
                                                int K, int N){
  __shared__ float t[32][33];
  int n0 = blockIdx.x * 32, k0 = blockIdx.y * 32;
  int tx = threadIdx.x & 31, ty = threadIdx.x >> 5;
#pragma unroll
  for (int i = 0; i < 4; i++){
    int kk = ty * 4 + i;
    t[kk][tx] = W[(size_t)(k0 + kk) * N + n0 + tx];
  }
  __syncthreads();
#pragma unroll
  for (int i = 0; i < 4; i++){
    int nn = ty * 4 + i;
    Wt[(size_t)(n0 + nn) * K + k0 + tx] = f2bf(t[tx][nn]);
  }
}

// ---------- layernorm: fp32 row -> bf16 row ----------
__global__ __launch_bounds__(256) void ln_k(const float* __restrict__ x,
                                            const float* __restrict__ g,
                                            const float* __restrict__ b,
                                            unsigned short* __restrict__ out){
  __shared__ float red[4];
  int row = blockIdx.x, tid = threadIdx.x;
  const float* xr = x + (size_t)row * DD;
  float4 v = *(const float4*)(xr + tid * 4);
  float s = v.x + v.y + v.z + v.w;
#pragma unroll
  for (int off = 32; off; off >>= 1) s += __shfl_xor(s, off);
  if ((tid & 63) == 0) red[tid >> 6] = s;
  __syncthreads();
  float mu = (red[0] + red[1] + red[2] + red[3]) * (1.f / DD);
  __syncthreads();
  float dx = v.x - mu, dy = v.y - mu, dz = v.z - mu, dw = v.w - mu;
  float sq = dx*dx + dy*dy + dz*dz + dw*dw;
#pragma unroll
  for (int off = 32; off; off >>= 1) sq += __shfl_xor(sq, off);
  if ((tid & 63) == 0) red[tid >> 6] = sq;
  __syncthreads();
  float var = (red[0] + red[1] + red[2] + red[3]) * (1.f / DD);
  float inv = rsqrtf(var + 1e-5f);
  float4 gv = *(const float4*)(g + tid * 4);
  float4 bv = *(const float4*)(b + tid * 4);
  unsigned short* orow = out + (size_t)row * DD + tid * 4;
  orow[0] = f2bf(dx * inv * gv.x + bv.x);
  orow[1] = f2bf(dy * inv * gv.y + bv.y);
  orow[2] = f2bf(dz * inv * gv.z + bv.z);
  orow[3] = f2bf(dw * inv * gv.w + bv.w);
}

// ---------- bf16 MFMA GEMM: C = A[M][K] @ Bt[N][K]^T + bias (+epilogue) ----------
#define BMT 128
#define BNT 128
#define BKT 32
#define LP 56

template<int EPI>
__global__ __launch_bounds__(256) void gemm_k(const unsigned short* __restrict__ A,
                                              const unsigned short* __restrict__ Bt,
                                              const float* __restrict__ bias,
                                              const float* __restrict__ res,
                                              void* __restrict__ Cout,
                                              int M, int N, int K){
  __shared__ unsigned short As[BMT * LP];
  __shared__ unsigned short Bs[BNT * LP];
  int tid = threadIdx.x;
  int row0 = blockIdx.x * BMT, col0 = blockIdx.y * BNT;
  int wid = tid >> 6, lane = tid & 63;
  int wm = (wid >> 1) * 64, wn = (wid & 1) * 64;
  int lr = lane & 15, lg = lane >> 4;
  f32x4 acc[4][4] = {};
  int sr = tid >> 1, sc = (tid & 1) * 16;
  const unsigned short* ag = A + (size_t)(row0 + sr) * K + sc;
  const unsigned short* bg = Bt + (size_t)(col0 + sr) * K + sc;
  for (int k0 = 0; k0 < K; k0 += BKT){
    uint4 a0 = *(const uint4*)(ag + k0);
    uint4 a1 = *(const uint4*)(ag + k0 + 8);
    uint4 b0 = *(const uint4*)(bg + k0);
    uint4 b1 = *(const uint4*)(bg + k0 + 8);
    __syncthreads();
    *(uint4*)&As[sr * LP + sc]     = a0;
    *(uint4*)&As[sr * LP + sc + 8] = a1;
    *(uint4*)&Bs[sr * LP + sc]     = b0;
    *(uint4*)&Bs[sr * LP + sc + 8] = b1;
    __syncthreads();
    bf16x8 af[4], bf[4];
#pragma unroll
    for (int mt = 0; mt < 4; mt++)
      af[mt] = *(const bf16x8*)&As[(wm + mt*16 + lr) * LP + lg * 8];
#pragma unroll
    for (int nt = 0; nt < 4; nt++)
      bf[nt] = *(const bf16x8*)&Bs[(wn + nt*16 + lr) * LP + lg * 8];
#pragma unroll
    for (int mt = 0; mt < 4; mt++)
#pragma unroll
      for (int nt = 0; nt < 4; nt++)
        acc[mt][nt] = MFMA(af[mt], bf[nt], acc[mt][nt]);
  }
#pragma unroll
  for (int mt = 0; mt < 4; mt++){
#pragma unroll
    for (int r = 0; r < 4; r++){
      int gr = row0 + wm + mt*16 + lg*4 + r;
#pragma unroll
      for (int nt = 0; nt < 4; nt++){
        int gc = col0 + wn + nt*16 + lr;
        float val = acc[mt][nt][r] + bias[gc];
        if constexpr (EPI == 1){
          val = 0.5f * val * (1.f + erff(val * 0.70710678118f));
        }
        if constexpr (EPI == 2){
          float ov = val + res[(size_t)gr * N + gc];
          ((float*)Cout)[(size_t)gr * N + gc] = ov;
        } else {
          ((unsigned short*)Cout)[(size_t)gr * N + gc] = f2bf(val);
        }
      }
    }
  }
}

// ---------- RoPE in-place on [rows][64] bf16, NEGATED rotation (verified r8) ----------
// pair (d, d+32): x1' = x1*c + x2*s ; x2' = x2*c - x1*s
__global__ __launch_bounds__(256) void rope_k(unsigned short* buf, int nheads){
  int idx = blockIdx.x * 8 + (threadIdx.x >> 5);
  int d = threadIdx.x & 31;
  int t = (idx / nheads) % TT;
  unsigned short* p = buf + (size_t)idx * HDW;
  float x1 = bf2f(p[d]);
  float x2 = bf2f(p[d + 32]);
  float theta = powf(10000.f, -(float)d * (1.f / 32.f));
  float c, s;
  sincosf((float)t * theta, &c, &s);
  p[d]      = f2bf(x1 * c + x2 * s);
  p[d + 32] = f2bf(x2 * c - x1 * s);
}

// ---------- V transpose: v[b][t][kvh][d] -> vt[b][kvh][d][t] (bf16) ----------
__global__ __launch_bounds__(256) void vtrans_k(const unsigned short* __restrict__ v,
                                                unsigned short* __restrict__ vt){
  __shared__ unsigned short tile[64][72];
  int t0 = blockIdx.x * 64;
  int kvh = blockIdx.y, b = blockIdx.z;
  int i = threadIdx.x;
  int tl = i >> 2, dc = (i & 3) * 16;
  const unsigned short* src = v + ((size_t)((b * TT + t0 + tl) * KVHN) + kvh) * HDW + dc;
  *(uint4*)&tile[tl][dc]     = *(const uint4*)src;
  *(uint4*)&tile[tl][dc + 8] = *(const uint4*)(src + 8);
  __syncthreads();
  int d = i >> 2, tc = (i & 3) * 16;
  unsigned short tmp[16];
#pragma unroll
  for (int e = 0; e < 16; e++) tmp[e] = tile[tc + e][d];
  unsigned short* dst = vt + ((size_t)((b * KVHN + kvh) * HDW) + d) * TT + t0 + tc;
  *(uint4*)dst       = *(uint4*)tmp;
  *(uint4*)(dst + 8) = *(uint4*)(tmp + 8);
}

// ---------- flash attention, 1 wave per (b, h, 32-row q-tile) ----------
__global__ __launch_bounds__(64) void attn_k(const unsigned short* __restrict__ q,
                                             const unsigned short* __restrict__ k,
                                             const unsigned short* __restrict__ vt,
                                             unsigned short* __restrict__ o){
  __shared__ unsigned short P[32 * 40];
  __shared__ float sc_l[32];
  int qt = blockIdx.x, h = blockIdx.y, b = blockIdx.z;
  int kvh = h >> 2;
  int lane = threadIdx.x;
  int lr = lane & 15, lg = lane >> 4;
  int q0 = qt * 32;
  bf16x8 qf[2][2];
#pragma unroll
  for (int qi = 0; qi < 2; qi++)
#pragma unroll
    for (int ks = 0; ks < 2; ks++)
      qf[qi][ks] = *(const bf16x8*)(q + ((size_t)((b*TT + q0 + qi*16 + lr) * HH) + h) * HDW + ks*32 + lg*8);
  f32x4 oa[2][4] = {};
  float m_st[2] = {-1e30f, -1e30f};
  float l_st[2] = {0.f, 0.f};
  int kt_lo = (q0 - (WIN - 1)) > 0 ? ((q0 - (WIN - 1)) >> 5) : 0;
  int kt_hi = (q0 + 31) >> 5;
  for (int kt = kt_lo; kt <= kt_hi; kt++){
    int kb = kt * 32;
    bf16x8 kf[2][2];
#pragma unroll
    for (int ki = 0; ki < 2; ki++)
#pragma unroll
      for (int ks = 0; ks < 2; ks++)
        kf[ki][ks] = *(const bf16x8*)(k + ((size_t)((b*TT + kb + ki*16 + lr) * KVHN) + kvh) * HDW + ks*32 + lg*8);
    f32x4 s[2][2] = {};
#pragma unroll
    for (int ki = 0; ki < 2; ki++)
#pragma unroll
      for (int qi = 0; qi < 2; qi++){
        s[ki][qi] = MFMA(kf[ki][0], qf[qi][0], s[ki][qi]);
        s[ki][qi] = MFMA(kf[ki][1], qf[qi][1], s[ki][qi]);
      }
#pragma unroll
    for (int qi = 0; qi < 2; qi++){
      int qa = q0 + qi*16 + lr;
      float pv[8];
      float mx = -1e30f;
#pragma unroll
      for (int ki = 0; ki < 2; ki++)
#pragma unroll
        for (int r = 0; r < 4; r++){
          int ka = kb + ki*16 + lg*4 + r;
          float val = s[ki][qi][r] * 0.125f;
          bool ok = (ka <= qa) && (qa - ka < WIN);
          val = ok ? val : -1e9f;
          pv[ki*4 + r] = val;
          mx = fmaxf(mx, val);
        }
      mx = fmaxf(mx, __shfl_xor(mx, 16));
      mx = fmaxf(mx, __shfl_xor(mx, 32));
      float mn = fmaxf(m_st[qi], mx);
      float scl = __expf(m_st[qi] - mn);
      m_st[qi] = mn;
      float ls = 0.f;
#pragma unroll
      for (int j = 0; j < 8; j++){ float p = __expf(pv[j] - mn); pv[j] = p; ls += p; }
      ls += __shfl_xor(ls, 16);
      ls += __shfl_xor(ls, 32);
      l_st[qi] = l_st[qi] * scl + ls;
#pragma unroll
      for (int ki = 0; ki < 2; ki++){
        uint2 w;
        w.x = (unsigned)f2bf(pv[ki*4+0]) | ((unsigned)f2bf(pv[ki*4+1]) << 16);
        w.y = (unsigned)f2bf(pv[ki*4+2]) | ((unsigned)f2bf(pv[ki*4+3]) << 16);
        *(uint2*)&P[(qi*16 + lr) * 40 + ki*16 + lg*4] = w;
      }
      if (lg == 0) sc_l[qi*16 + lr] = scl;
    }
    __syncthreads();
#pragma unroll
    for (int qi = 0; qi < 2; qi++)
#pragma unroll
      for (int r = 0; r < 4; r++){
        float f = sc_l[qi*16 + lg*4 + r];
#pragma unroll
        for (int di = 0; di < 4; di++) oa[qi][di][r] *= f;
      }
    bf16x8 pa[2];
#pragma unroll
    for (int qi = 0; qi < 2; qi++)
      pa[qi] = *(const bf16x8*)&P[(qi*16 + lr) * 40 + lg*8];
#pragma unroll
    for (int di = 0; di < 4; di++){
      bf16x8 vb = *(const bf16x8*)(vt + ((size_t)((b*KVHN + kvh) * HDW) + di*16 + lr) * TT + kb + lg*8);
#pragma unroll
      for (int qi = 0; qi < 2; qi++)
        oa[qi][di] = MFMA(pa[qi], vb, oa[qi][di]);
    }
    __syncthreads();
  }
  if (lg == 0){ sc_l[lr] = l_st[0]; sc_l[16 + lr] = l_st[1]; }
  __syncthreads();
#pragma unroll
  for (int qi = 0; qi < 2; qi++)
#pragma unroll
    for (int r = 0; r < 4; r++){
      float inv = 1.f / sc_l[qi*16 + lg*4 + r];
      int t = q0 + qi*16 + lg*4 + r;
#pragma unroll
      for (int di = 0; di < 4; di++)
        o[((size_t)((b*TT + t) * HH) + h) * HDW + di*16 + lr] = f2bf(oa[qi][di][r] * inv);
    }
}

extern "C" void kernel_launch(void* const* d_in, const int* in_sizes, int n_in,
                              void* d_out, int out_size, void* d_ws, size_t ws_size,
                              hipStream_t stream){
  const float* x   = (const float*)d_in[0];
  const float* Wq  = (const float*)d_in[1];
  const float* bq  = (const float*)d_in[2];
  const float* Wk  = (const float*)d_in[3];
  const float* bk  = (const float*)d_in[4];
  const float* Wv  = (const float*)d_in[5];
  const float* bv  = (const float*)d_in[6];
  const float* Wo  = (const float*)d_in[7];
  const float* bo  = (const float*)d_in[8];
  const float* g1  = (const float*)d_in[9];
  const float* b1  = (const float*)d_in[10];
  const float* Wf1 = (const float*)d_in[11];
  const float* bf1 = (const float*)d_in[12];
  const float* Wf2 = (const float*)d_in[13];
  const float* bf2 = (const float*)d_in[14];
  const float* g2  = (const float*)d_in[15];
  const float* b2  = (const float*)d_in[16];

  static const int want[17] = {4194304, 1048576, 1024, 262144, 256, 262144, 256,
                               1048576, 1024, 1024, 1024, 4194304, 4096, 4194304,
                               1024, 1024, 1024};
  bool bad = (n_in != 17) || (out_size != 4194304);
  if (!bad) for (int i = 0; i < 17; i++) if (in_sizes[i] != want[i]) bad = true;
  if (bad){
    zero_k<<<2048, 256, 0, stream>>>((float*)d_out, out_size);
    return;
  }

  const int M = 4 * TT;  // 4096 rows
  char* ws = (char*)d_ws;
  size_t off = 0;
  auto alloc = [&](size_t bytes) -> void* {
    void* p = ws + off; off += (bytes + 255) & ~(size_t)255; return p;
  };
  unsigned short* wtq  = (unsigned short*)alloc((size_t)DD * DD * 2);
  unsigned short* wtk  = (unsigned short*)alloc((size_t)256 * DD * 2);
  unsigned short* wtv  = (unsigned short*)alloc((size_t)256 * DD * 2);
  unsigned short* wto  = (unsigned short*)alloc((size_t)DD * DD * 2);
  unsigned short* wtf1 = (unsigned short*)alloc((size_t)DFFN * DD * 2);
  unsigned short* wtf2 = (unsigned short*)alloc((size_t)DD * DFFN * 2);
  unsigned short* h1   = (unsigned short*)alloc((size_t)M * DD * 2);
  unsigned short* qb   = (unsigned short*)alloc((size_t)M * DD * 2);
  unsigned short* kb   = (unsigned short*)alloc((size_t)M * 256 * 2);
  unsigned short* vb   = (unsigned short*)alloc((size_t)M * 256 * 2);
  unsigned short* vtb  = (unsigned short*)alloc((size_t)M * 256 * 2);
  unsigned short* ao   = (unsigned short*)alloc((size_t)M * DD * 2);
  float*          x2   = (float*)alloc((size_t)M * DD * 4);
  unsigned short* h2   = h1;            // reuse
  unsigned short* ff   = (unsigned short*)alloc((size_t)M * DFFN * 2);
  (void)ws_size;

  // weights -> bf16 transposed
  wtrans_k<<<dim3(DD/32,  DD/32),  256, 0, stream>>>(Wq,  wtq,  DD,  DD);
  wtrans_k<<<dim3(256/32, DD/32),  256, 0, stream>>>(Wk,  wtk,  DD,  256);
  wtrans_k<<<dim3(256/32, DD/32),  256, 0, stream>>>(Wv,  wtv,  DD,  256);
  wtrans_k<<<dim3(DD/32,  DD/32),  256, 0, stream>>>(Wo,  wto,  DD,  DD);
  wtrans_k<<<dim3(DFFN/32,DD/32),  256, 0, stream>>>(Wf1, wtf1, DD,  DFFN);
  wtrans_k<<<dim3(DD/32,  DFFN/32),256, 0, stream>>>(Wf2, wtf2, DFFN,DD);

  // LN1
  ln_k<<<M, 256, 0, stream>>>(x, g1, b1, h1);

  // QKV
  gemm_k<0><<<dim3(M/BMT, DD/BNT),  256, 0, stream>>>(h1, wtq, bq, nullptr, qb, M, DD,  DD);
  gemm_k<0><<<dim3(M/BMT, 256/BNT), 256, 0, stream>>>(h1, wtk, bk, nullptr, kb, M, 256, DD);
  gemm_k<0><<<dim3(M/BMT, 256/BNT), 256, 0, stream>>>(h1, wtv, bv, nullptr, vb, M, 256, DD);

  // RoPE (negated rotation, verified r8)
  rope_k<<<(M * HH) / 8,   256, 0, stream>>>(qb, HH);
  rope_k<<<(M * KVHN) / 8, 256, 0, stream>>>(kb, KVHN);

  // V transpose
  vtrans_k<<<dim3(TT/64, KVHN, 4), 256, 0, stream>>>(vb, vtb);

  // attention (MFMA flash)
  attn_k<<<dim3(TT/32, HH, 4), 64, 0, stream>>>(qb, kb, vtb, ao);

  // Wo + residual (fp32 out)
  gemm_k<2><<<dim3(M/BMT, DD/BNT), 256, 0, stream>>>(ao, wto, bo, x, x2, M, DD, DD);

  // LN2
  ln_k<<<M, 256, 0, stream>>>(x2, g2, b2, h2);

  // FFN
  gemm_k<1><<<dim3(M/BMT, DFFN/BNT), 256, 0, stream>>>(h2, wtf1, bf1, nullptr, ff, M, DFFN, DD);
  gemm_k<2><<<dim3(M/BMT, DD/BNT),   256, 0, stream>>>(ff, wtf2, bf2, x2, (float*)d_out, M, DD, DFFN);
}

// Round 10
// 337.316 us; speedup vs baseline: 8.9950x; 1.0881x over previous
//
#include <hip/hip_runtime.h>
#include <hip/hip_bf16.h>
#include <math.h>

#define TT 1024
#define DD 1024
#define HH 16
#define KVHN 4
#define HDW 64
#define DFFN 4096
#define WIN 256

typedef __attribute__((ext_vector_type(4))) float f32x4;
typedef __attribute__((ext_vector_type(8))) __bf16 bf16x8;

typedef const __attribute__((address_space(1))) void gas_t;
typedef __attribute__((address_space(3))) void las_t;

__device__ inline unsigned short f2bf(float f){
  union { float f; unsigned u; } x; x.f = f;
  unsigned r = x.u + 0x7fffu + ((x.u >> 16) & 1u);
  return (unsigned short)(r >> 16);
}
__device__ inline float bf2f(unsigned short b){
  union { unsigned u; float f; } x; x.u = ((unsigned)b) << 16; return x.f;
}
__device__ inline f32x4 MFMA(bf16x8 a, bf16x8 b, f32x4 c){
  return __builtin_amdgcn_mfma_f32_16x16x32_bf16(a, b, c, 0, 0, 0);
}

__global__ void zero_k(float* out, int n){
  for (int i = blockIdx.x * blockDim.x + threadIdx.x; i < n; i += gridDim.x * blockDim.x)
    out[i] = 0.f;
}

// ---------- weight transpose: W[K][N] fp32 -> Wt[N][K] bf16 ----------
__global__ __launch_bounds__(256) void wtrans_k(const float* __restrict__ W,
                                                unsigned short* __restrict__ Wt,
                                                int K, int N){
  __shared__ float t[32][33];
  int n0 = blockIdx.x * 32, k0 = blockIdx.y * 32;
  int tx = threadIdx.x & 31, ty = threadIdx.x >> 5;
#pragma unroll
  for (int i = 0; i < 4; i++){
    int kk = ty * 4 + i;
    t[kk][tx] = W[(size_t)(k0 + kk) * N + n0 + tx];
  }
  __syncthreads();
#pragma unroll
  for (int i = 0; i < 4; i++){
    int nn = ty * 4 + i;
    Wt[(size_t)(n0 + nn) * K + k0 + tx] = f2bf(t[tx][nn]);
  }
}

// ---------- layernorm: fp32 row -> bf16 row ----------
__global__ __launch_bounds__(256) void ln_k(const float* __restrict__ x,
                                            const float* __restrict__ g,
                                            const float* __restrict__ b,
                                            unsigned short* __restrict__ out){
  __shared__ float red[4];
  int row = blockIdx.x, tid = threadIdx.x;
  const float* xr = x + (size_t)row * DD;
  float4 v = *(const float4*)(xr + tid * 4);
  float s = v.x + v.y + v.z + v.w;
#pragma unroll
  for (int off = 32; off; off >>= 1) s += __shfl_xor(s, off);
  if ((tid & 63) == 0) red[tid >> 6] = s;
  __syncthreads();
  float mu = (red[0] + red[1] + red[2] + red[3]) * (1.f / DD);
  __syncthreads();
  float dx = v.x - mu, dy = v.y - mu, dz = v.z - mu, dw = v.w - mu;
  float sq = dx*dx + dy*dy + dz*dz + dw*dw;
#pragma unroll
  for (int off = 32; off; off >>= 1) sq += __shfl_xor(sq, off);
  if ((tid & 63) == 0) red[tid >> 6] = sq;
  __syncthreads();
  float var = (red[0] + red[1] + red[2] + red[3]) * (1.f / DD);
  float inv = rsqrtf(var + 1e-5f);
  float4 gv = *(const float4*)(g + tid * 4);
  float4 bv = *(const float4*)(b + tid * 4);
  unsigned short* orow = out + (size_t)row * DD + tid * 4;
  orow[0] = f2bf(dx * inv * gv.x + bv.x);
  orow[1] = f2bf(dy * inv * gv.y + bv.y);
  orow[2] = f2bf(dz * inv * gv.z + bv.z);
  orow[3] = f2bf(dw * inv * gv.w + bv.w);
}

// ---------- bf16 MFMA GEMM, m97 structure: global_load_lds(16B) -> linear LDS ----------
// C = A[M][K] @ Bt[N][K]^T + bias. EPI 0: bf16. 1: GELU bf16. 2: +res fp32.
template<int EPI>
__global__ __launch_bounds__(256) void gemm_k(const unsigned short* __restrict__ A,
                                              const unsigned short* __restrict__ Bt,
                                              const float* __restrict__ bias,
                                              const float* __restrict__ res,
                                              void* __restrict__ Cout,
                                              int M, int N, int K){
  __shared__ unsigned short As[128 * 32];   // linear [row][k] — REQUIRED by global_load_lds
  __shared__ unsigned short Bs[128 * 32];
  int tid = threadIdx.x;
  int row0 = blockIdx.x * 128, col0 = blockIdx.y * 128;
  int wid = tid >> 6, lane = tid & 63;
  int wm = (wid >> 1) * 64, wn = (wid & 1) * 64;
  int lr = lane & 15, lg = lane >> 4;
  f32x4 acc[4][4] = {};

  // staging: lane i of wave w covers row w*16 + i/4, elems (i&3)*8 .. +8 (16B)
  int srow = wid * 16 + (lane >> 2);
  int scol = (lane & 3) * 8;
  const unsigned short* gA0 = A  + (size_t)(row0 + srow) * K + scol;
  const unsigned short* gA1 = A  + (size_t)(row0 + 64 + srow) * K + scol;
  const unsigned short* gB0 = Bt + (size_t)(col0 + srow) * K + scol;
  const unsigned short* gB1 = Bt + (size_t)(col0 + 64 + srow) * K + scol;
  unsigned short* lA0 = As + wid * 512;          // wave-uniform base (bytes: wid*1024)
  unsigned short* lA1 = As + 2048 + wid * 512;
  unsigned short* lB0 = Bs + wid * 512;
  unsigned short* lB1 = Bs + 2048 + wid * 512;

  for (int k0 = 0; k0 < K; k0 += 32){
    __syncthreads();   // LDS safe to overwrite
    __builtin_amdgcn_global_load_lds((gas_t*)(gA0 + k0), (las_t*)lA0, 16, 0, 0);
    __builtin_amdgcn_global_load_lds((gas_t*)(gA1 + k0), (las_t*)lA1, 16, 0, 0);
    __builtin_amdgcn_global_load_lds((gas_t*)(gB0 + k0), (las_t*)lB0, 16, 0, 0);
    __builtin_amdgcn_global_load_lds((gas_t*)(gB1 + k0), (las_t*)lB1, 16, 0, 0);
    __syncthreads();   // compiler drains vmcnt before barrier
    bf16x8 af[4], bf[4];
#pragma unroll
    for (int mt = 0; mt < 4; mt++)
      af[mt] = *(const bf16x8*)&As[(wm + mt*16 + lr) * 32 + lg * 8];
#pragma unroll
    for (int nt = 0; nt < 4; nt++)
      bf[nt] = *(const bf16x8*)&Bs[(wn + nt*16 + lr) * 32 + lg * 8];
#pragma unroll
    for (int mt = 0; mt < 4; mt++)
#pragma unroll
      for (int nt = 0; nt < 4; nt++)
        acc[mt][nt] = MFMA(af[mt], bf[nt], acc[mt][nt]);
  }
#pragma unroll
  for (int mt = 0; mt < 4; mt++){
#pragma unroll
    for (int r = 0; r < 4; r++){
      int gr = row0 + wm + mt*16 + lg*4 + r;
#pragma unroll
      for (int nt = 0; nt < 4; nt++){
        int gc = col0 + wn + nt*16 + lr;
        float val = acc[mt][nt][r] + bias[gc];
        if constexpr (EPI == 1){
          val = 0.5f * val * (1.f + erff(val * 0.70710678118f));
        }
        if constexpr (EPI == 2){
          float ov = val + res[(size_t)gr * N + gc];
          ((float*)Cout)[(size_t)gr * N + gc] = ov;
        } else {
          ((unsigned short*)Cout)[(size_t)gr * N + gc] = f2bf(val);
        }
      }
    }
  }
}

// ---------- RoPE in-place, NEGATED rotation (verified r8) ----------
__global__ __launch_bounds__(256) void rope_k(unsigned short* buf, int nheads){
  int idx = blockIdx.x * 8 + (threadIdx.x >> 5);
  int d = threadIdx.x & 31;
  int t = (idx / nheads) % TT;
  unsigned short* p = buf + (size_t)idx * HDW;
  float x1 = bf2f(p[d]);
  float x2 = bf2f(p[d + 32]);
  float theta = powf(10000.f, -(float)d * (1.f / 32.f));
  float c, s;
  sincosf((float)t * theta, &c, &s);
  p[d]      = f2bf(x1 * c + x2 * s);
  p[d + 32] = f2bf(x2 * c - x1 * s);
}

// ---------- V transpose: v[b][t][kvh][d] -> vt[b][kvh][d][t] (bf16) ----------
__global__ __launch_bounds__(256) void vtrans_k(const unsigned short* __restrict__ v,
                                                unsigned short* __restrict__ vt){
  __shared__ unsigned short tile[64][72];
  int t0 = blockIdx.x * 64;
  int kvh = blockIdx.y, b = blockIdx.z;
  int i = threadIdx.x;
  int tl = i >> 2, dc = (i & 3) * 16;
  const unsigned short* src = v + ((size_t)((b * TT + t0 + tl) * KVHN) + kvh) * HDW + dc;
  *(uint4*)&tile[tl][dc]     = *(const uint4*)src;
  *(uint4*)&tile[tl][dc + 8] = *(const uint4*)(src + 8);
  __syncthreads();
  int d = i >> 2, tc = (i & 3) * 16;
  unsigned short tmp[16];
#pragma unroll
  for (int e = 0; e < 16; e++) tmp[e] = tile[tc + e][d];
  unsigned short* dst = vt + ((size_t)((b * KVHN + kvh) * HDW) + d) * TT + t0 + tc;
  *(uint4*)dst       = *(uint4*)tmp;
  *(uint4*)(dst + 8) = *(uint4*)(tmp + 8);
}

// ---------- flash attention, 1 wave per (b, h, 32-row q-tile) ----------
__global__ __launch_bounds__(64) void attn_k(const unsigned short* __restrict__ q,
                                             const unsigned short* __restrict__ k,
                                             const unsigned short* __restrict__ vt,
                                             unsigned short* __restrict__ o){
  __shared__ unsigned short P[32 * 40];
  __shared__ float sc_l[32];
  int qt = blockIdx.x, h = blockIdx.y, b = blockIdx.z;
  int kvh = h >> 2;
  int lane = threadIdx.x;
  int lr = lane & 15, lg = lane >> 4;
  int q0 = qt * 32;
  bf16x8 qf[2][2];
#pragma unroll
  for (int qi = 0; qi < 2; qi++)
#pragma unroll
    for (int ks = 0; ks < 2; ks++)
      qf[qi][ks] = *(const bf16x8*)(q + ((size_t)((b*TT + q0 + qi*16 + lr) * HH) + h) * HDW + ks*32 + lg*8);
  f32x4 oa[2][4] = {};
  float m_st[2] = {-1e30f, -1e30f};
  float l_st[2] = {0.f, 0.f};
  int kt_lo = (q0 - (WIN - 1)) > 0 ? ((q0 - (WIN - 1)) >> 5) : 0;
  int kt_hi = (q0 + 31) >> 5;
  for (int kt = kt_lo; kt <= kt_hi; kt++){
    int kb = kt * 32;
    bf16x8 kf[2][2];
#pragma unroll
    for (int ki = 0; ki < 2; ki++)
#pragma unroll
      for (int ks = 0; ks < 2; ks++)
        kf[ki][ks] = *(const bf16x8*)(k + ((size_t)((b*TT + kb + ki*16 + lr) * KVHN) + kvh) * HDW + ks*32 + lg*8);
    f32x4 s[2][2] = {};
#pragma unroll
    for (int ki = 0; ki < 2; ki++)
#pragma unroll
      for (int qi = 0; qi < 2; qi++){
        s[ki][qi] = MFMA(kf[ki][0], qf[qi][0], s[ki][qi]);
        s[ki][qi] = MFMA(kf[ki][1], qf[qi][1], s[ki][qi]);
      }
#pragma unroll
    for (int qi = 0; qi < 2; qi++){
      int qa = q0 + qi*16 + lr;
      float pv[8];
      float mx = -1e30f;
#pragma unroll
      for (int ki = 0; ki < 2; ki++)
#pragma unroll
        for (int r = 0; r < 4; r++){
          int ka = kb + ki*16 + lg*4 + r;
          float val = s[ki][qi][r] * 0.125f;
          bool ok = (ka <= qa) && (qa - ka < WIN);
          val = ok ? val : -1e9f;
          pv[ki*4 + r] = val;
          mx = fmaxf(mx, val);
        }
      mx = fmaxf(mx, __shfl_xor(mx, 16));
      mx = fmaxf(mx, __shfl_xor(mx, 32));
      float mn = fmaxf(m_st[qi], mx);
      float scl = __expf(m_st[qi] - mn);
      m_st[qi] = mn;
      float ls = 0.f;
#pragma unroll
      for (int j = 0; j < 8; j++){ float p = __expf(pv[j] - mn); pv[j] = p; ls += p; }
      ls += __shfl_xor(ls, 16);
      ls += __shfl_xor(ls, 32);
      l_st[qi] = l_st[qi] * scl + ls;
#pragma unroll
      for (int ki = 0; ki < 2; ki++){
        uint2 w;
        w.x = (unsigned)f2bf(pv[ki*4+0]) | ((unsigned)f2bf(pv[ki*4+1]) << 16);
        w.y = (unsigned)f2bf(pv[ki*4+2]) | ((unsigned)f2bf(pv[ki*4+3]) << 16);
        *(uint2*)&P[(qi*16 + lr) * 40 + ki*16 + lg*4] = w;
      }
      if (lg == 0) sc_l[qi*16 + lr] = scl;
    }
    __syncthreads();
#pragma unroll
    for (int qi = 0; qi < 2; qi++)
#pragma unroll
      for (int r = 0; r < 4; r++){
        float f = sc_l[qi*16 + lg*4 + r];
#pragma unroll
        for (int di = 0; di < 4; di++) oa[qi][di][r] *= f;
      }
    bf16x8 pa[2];
#pragma unroll
    for (int qi = 0; qi < 2; qi++)
      pa[qi] = *(const bf16x8*)&P[(qi*16 + lr) * 40 + lg*8];
#pragma unroll
    for (int di = 0; di < 4; di++){
      bf16x8 vb = *(const bf16x8*)(vt + ((size_t)((b*KVHN + kvh) * HDW) + di*16 + lr) * TT + kb + lg*8);
#pragma unroll
      for (int qi = 0; qi < 2; qi++)
        oa[qi][di] = MFMA(pa[qi], vb, oa[qi][di]);
    }
    __syncthreads();
  }
  if (lg == 0){ sc_l[lr] = l_st[0]; sc_l[16 + lr] = l_st[1]; }
  __syncthreads();
#pragma unroll
  for (int qi = 0; qi < 2; qi++)
#pragma unroll
    for (int r = 0; r < 4; r++){
      float inv = 1.f / sc_l[qi*16 + lg*4 + r];
      int t = q0 + qi*16 + lg*4 + r;
#pragma unroll
      for (int di = 0; di < 4; di++)
        o[((size_t)((b*TT + t) * HH) + h) * HDW + di*16 + lr] = f2bf(oa[qi][di][r] * inv);
    }
}

extern "C" void kernel_launch(void* const* d_in, const int* in_sizes, int n_in,
                              void* d_out, int out_size, void* d_ws, size_t ws_size,
                              hipStream_t stream){
  const float* x   = (const float*)d_in[0];
  const float* Wq  = (const float*)d_in[1];
  const float* bq  = (const float*)d_in[2];
  const float* Wk  = (const float*)d_in[3];
  const float* bk  = (const float*)d_in[4];
  const float* Wv  = (const float*)d_in[5];
  const float* bv  = (const float*)d_in[6];
  const float* Wo  = (const float*)d_in[7];
  const float* bo  = (const float*)d_in[8];
  const float* g1  = (const float*)d_in[9];
  const float* b1  = (const float*)d_in[10];
  const float* Wf1 = (const float*)d_in[11];
  const float* bf1 = (const float*)d_in[12];
  const float* Wf2 = (const float*)d_in[13];
  const float* bf2 = (const float*)d_in[14];
  const float* g2  = (const float*)d_in[15];
  const float* b2  = (const float*)d_in[16];

  static const int want[17] = {4194304, 1048576, 1024, 262144, 256, 262144, 256,
                               1048576, 1024, 1024, 1024, 4194304, 4096, 4194304,
                               1024, 1024, 1024};
  bool bad = (n_in != 17) || (out_size != 4194304);
  if (!bad) for (int i = 0; i < 17; i++) if (in_sizes[i] != want[i]) bad = true;
  if (bad){
    zero_k<<<2048, 256, 0, stream>>>((float*)d_out, out_size);
    return;
  }

  const int M = 4 * TT;  // 4096 rows
  char* ws = (char*)d_ws;
  size_t off = 0;
  auto alloc = [&](size_t bytes) -> void* {
    void* p = ws + off; off += (bytes + 255) & ~(size_t)255; return p;
  };
  unsigned short* wtq  = (unsigned short*)alloc((size_t)DD * DD * 2);
  unsigned short* wtk  = (unsigned short*)alloc((size_t)256 * DD * 2);
  unsigned short* wtv  = (unsigned short*)alloc((size_t)256 * DD * 2);
  unsigned short* wto  = (unsigned short*)alloc((size_t)DD * DD * 2);
  unsigned short* wtf1 = (unsigned short*)alloc((size_t)DFFN * DD * 2);
  unsigned short* wtf2 = (unsigned short*)alloc((size_t)DD * DFFN * 2);
  unsigned short* h1   = (unsigned short*)alloc((size_t)M * DD * 2);
  unsigned short* qb   = (unsigned short*)alloc((size_t)M * DD * 2);
  unsigned short* kb   = (unsigned short*)alloc((size_t)M * 256 * 2);
  unsigned short* vb   = (unsigned short*)alloc((size_t)M * 256 * 2);
  unsigned short* vtb  = (unsigned short*)alloc((size_t)M * 256 * 2);
  unsigned short* ao   = (unsigned short*)alloc((size_t)M * DD * 2);
  float*          x2   = (float*)alloc((size_t)M * DD * 4);
  unsigned short* h2   = h1;            // reuse
  unsigned short* ff   = (unsigned short*)alloc((size_t)M * DFFN * 2);
  (void)ws_size;

  // weights -> bf16 transposed
  wtrans_k<<<dim3(DD/32,  DD/32),  256, 0, stream>>>(Wq,  wtq,  DD,  DD);
  wtrans_k<<<dim3(256/32, DD/32),  256, 0, stream>>>(Wk,  wtk,  DD,  256);
  wtrans_k<<<dim3(256/32, DD/32),  256, 0, stream>>>(Wv,  wtv,  DD,  256);
  wtrans_k<<<dim3(DD/32,  DD/32),  256, 0, stream>>>(Wo,  wto,  DD,  DD);
  wtrans_k<<<dim3(DFFN/32,DD/32),  256, 0, stream>>>(Wf1, wtf1, DD,  DFFN);
  wtrans_k<<<dim3(DD/32,  DFFN/32),256, 0, stream>>>(Wf2, wtf2, DFFN,DD);

  // LN1
  ln_k<<<M, 256, 0, stream>>>(x, g1, b1, h1);

  // QKV
  gemm_k<0><<<dim3(M/128, DD/128),  256, 0, stream>>>(h1, wtq, bq, nullptr, qb, M, DD,  DD);
  gemm_k<0><<<dim3(M/128, 256/128), 256, 0, stream>>>(h1, wtk, bk, nullptr, kb, M, 256, DD);
  gemm_k<0><<<dim3(M/128, 256/128), 256, 0, stream>>>(h1, wtv, bv, nullptr, vb, M, 256, DD);

  // RoPE (negated rotation, verified r8)
  rope_k<<<(M * HH) / 8,   256, 0, stream>>>(qb, HH);
  rope_k<<<(M * KVHN) / 8, 256, 0, stream>>>(kb, KVHN);

  // V transpose
  vtrans_k<<<dim3(TT/64, KVHN, 4), 256, 0, stream>>>(vb, vtb);

  // attention (MFMA flash)
  attn_k<<<dim3(TT/32, HH, 4), 64, 0, stream>>>(qb, kb, vtb, ao);

  // Wo + residual (fp32 out)
  gemm_k<2><<<dim3(M/128, DD/128), 256, 0, stream>>>(ao, wto, bo, x, x2, M, DD, DD);

  // LN2
  ln_k<<<M, 256, 0, stream>>>(x2, g2, b2, h2);

  // FFN
  gemm_k<1><<<dim3(M/128, DFFN/128), 256, 0, stream>>>(h2, wtf1, bf1, nullptr, ff, M, DFFN, DD);
  gemm_k<2><<<dim3(M/128, DD/128),   256, 0, stream>>>(ff, wtf2, bf2, x2, (float*)d_out, M, DD, DFFN);
}

// Round 11
// 287.770 us; speedup vs baseline: 10.5437x; 1.1722x over previous
//
#include <hip/hip_runtime.h>
#include <hip/hip_bf16.h>
#include <math.h>

#define TT 1024
#define DD 1024
#define HH 16
#define KVHN 4
#define HDW 64
#define DFFN 4096
#define WIN 256

typedef __attribute__((ext_vector_type(4))) float f32x4;
typedef __attribute__((ext_vector_type(8))) __bf16 bf16x8;

typedef const __attribute__((address_space(1))) void gas_t;
typedef __attribute__((address_space(3))) void las_t;

__device__ inline unsigned short f2bf(float f){
  union { float f; unsigned u; } x; x.f = f;
  unsigned r = x.u + 0x7fffu + ((x.u >> 16) & 1u);
  return (unsigned short)(r >> 16);
}
__device__ inline float bf2f(unsigned short b){
  union { unsigned u; float f; } x; x.u = ((unsigned)b) << 16; return x.f;
}
__device__ inline f32x4 MFMA(bf16x8 a, bf16x8 b, f32x4 c){
  return __builtin_amdgcn_mfma_f32_16x16x32_bf16(a, b, c, 0, 0, 0);
}

__global__ void zero_k(float* out, int n){
  for (int i = blockIdx.x * blockDim.x + threadIdx.x; i < n; i += gridDim.x * blockDim.x)
    out[i] = 0.f;
}

// ---------- weight transpose: W[K][N] fp32 -> Wt[N][K] bf16 ----------
__global__ __launch_bounds__(256) void wtrans_k(const float* __restrict__ W,
                                                unsigned short* __restrict__ Wt,
                                                int K, int N){
  __shared__ float t[32][33];
  int n0 = blockIdx.x * 32, k0 = blockIdx.y * 32;
  int tx = threadIdx.x & 31, ty = threadIdx.x >> 5;
#pragma unroll
  for (int i = 0; i < 4; i++){
    int kk = ty * 4 + i;
    t[kk][tx] = W[(size_t)(k0 + kk) * N + n0 + tx];
  }
  __syncthreads();
#pragma unroll
  for (int i = 0; i < 4; i++){
    int nn = ty * 4 + i;
    Wt[(size_t)(n0 + nn) * K + k0 + tx] = f2bf(t[tx][nn]);
  }
}

// ---------- pack QKV bias ----------
__global__ void packb_k(const float* bq, const float* bk, const float* bv, float* o){
  int i = blockIdx.x * 256 + threadIdx.x;
  if (i < 1536)
    o[i] = (i < 1024) ? bq[i] : ((i < 1280) ? bk[i - 1024] : bv[i - 1280]);
}

// ---------- layernorm: fp32 row -> bf16 row ----------
__global__ __launch_bounds__(256) void ln_k(const float* __restrict__ x,
                                            const float* __restrict__ g,
                                            const float* __restrict__ b,
                                            unsigned short* __restrict__ out){
  __shared__ float red[4];
  int row = blockIdx.x, tid = threadIdx.x;
  const float* xr = x + (size_t)row * DD;
  float4 v = *(const float4*)(xr + tid * 4);
  float s = v.x + v.y + v.z + v.w;
#pragma unroll
  for (int off = 32; off; off >>= 1) s += __shfl_xor(s, off);
  if ((tid & 63) == 0) red[tid >> 6] = s;
  __syncthreads();
  float mu = (red[0] + red[1] + red[2] + red[3]) * (1.f / DD);
  __syncthreads();
  float dx = v.x - mu, dy = v.y - mu, dz = v.z - mu, dw = v.w - mu;
  float sq = dx*dx + dy*dy + dz*dz + dw*dw;
#pragma unroll
  for (int off = 32; off; off >>= 1) sq += __shfl_xor(sq, off);
  if ((tid & 63) == 0) red[tid >> 6] = sq;
  __syncthreads();
  float var = (red[0] + red[1] + red[2] + red[3]) * (1.f / DD);
  float inv = rsqrtf(var + 1e-5f);
  float4 gv = *(const float4*)(g + tid * 4);
  float4 bv = *(const float4*)(b + tid * 4);
  unsigned short* orow = out + (size_t)row * DD + tid * 4;
  orow[0] = f2bf(dx * inv * gv.x + bv.x);
  orow[1] = f2bf(dy * inv * gv.y + bv.y);
  orow[2] = f2bf(dz * inv * gv.z + bv.z);
  orow[3] = f2bf(dw * inv * gv.w + bv.w);
}

// ---------- bf16 MFMA GEMM: 2-phase dbuf + global_load_lds + XCD swizzle ----------
// C = A[M][K] @ Bt[N][K]^T + bias. EPI 0: bf16 (ldc=N). 1: GELU bf16. 2: +res fp32.
template<int EPI>
__global__ __launch_bounds__(256) void gemm_k(const unsigned short* __restrict__ A,
                                              const unsigned short* __restrict__ Bt,
                                              const float* __restrict__ bias,
                                              const float* __restrict__ res,
                                              void* __restrict__ Cout,
                                              int M, int N, int K){
  __shared__ unsigned short As[2][128 * 32];
  __shared__ unsigned short Bs[2][128 * 32];
  int tid = threadIdx.x;
  // bijective XCD remap (m204), column-major decomposition: consecutive blocks
  // on one XCD share the same weight (B) panel -> per-XCD L2 reuse
  int gx = gridDim.x;
  int nwg = gx * gridDim.y;
  int fid = blockIdx.y * gx + blockIdx.x;
  int q8 = nwg >> 3, r8 = nwg & 7;
  int xcd = fid & 7, loc = fid >> 3;
  int wg = (xcd < r8 ? xcd * (q8 + 1) : r8 * (q8 + 1) + (xcd - r8) * q8) + loc;
  int row0 = (wg % gx) * 128, col0 = (wg / gx) * 128;

  int wid = tid >> 6, lane = tid & 63;
  int wm = (wid >> 1) * 64, wn = (wid & 1) * 64;
  int lr = lane & 15, lg = lane >> 4;
  f32x4 acc[4][4] = {};

  int srow = wid * 16 + (lane >> 2);
  int scol = (lane & 3) * 8;
  const unsigned short* gA0 = A  + (size_t)(row0 + srow) * K + scol;
  const unsigned short* gA1 = A  + (size_t)(row0 + 64 + srow) * K + scol;
  const unsigned short* gB0 = Bt + (size_t)(col0 + srow) * K + scol;
  const unsigned short* gB1 = Bt + (size_t)(col0 + 64 + srow) * K + scol;

  int NT = K >> 5;
  // prologue: stage tile 0 -> buf 0
  __builtin_amdgcn_global_load_lds((gas_t*)gA0, (las_t*)&As[0][wid*512],        16, 0, 0);
  __builtin_amdgcn_global_load_lds((gas_t*)gA1, (las_t*)&As[0][2048 + wid*512], 16, 0, 0);
  __builtin_amdgcn_global_load_lds((gas_t*)gB0, (las_t*)&Bs[0][wid*512],        16, 0, 0);
  __builtin_amdgcn_global_load_lds((gas_t*)gB1, (las_t*)&Bs[0][2048 + wid*512], 16, 0, 0);
  __syncthreads();
  int cur = 0;
  for (int t = 0; t < NT; t++){
    if (t + 1 < NT){                       // issue next tile BEFORE compute
      int k0 = (t + 1) << 5;
      int nb = cur ^ 1;
      __builtin_amdgcn_global_load_lds((gas_t*)(gA0 + k0), (las_t*)&As[nb][wid*512],        16, 0, 0);
      __builtin_amdgcn_global_load_lds((gas_t*)(gA1 + k0), (las_t*)&As[nb][2048 + wid*512], 16, 0, 0);
      __builtin_amdgcn_global_load_lds((gas_t*)(gB0 + k0), (las_t*)&Bs[nb][wid*512],        16, 0, 0);
      __builtin_amdgcn_global_load_lds((gas_t*)(gB1 + k0), (las_t*)&Bs[nb][2048 + wid*512], 16, 0, 0);
    }
    bf16x8 af[4], bf[4];
#pragma unroll
    for (int mt = 0; mt < 4; mt++)
      af[mt] = *(const bf16x8*)&As[cur][(wm + mt*16 + lr) * 32 + lg * 8];
#pragma unroll
    for (int nt2 = 0; nt2 < 4; nt2++)
      bf[nt2] = *(const bf16x8*)&Bs[cur][(wn + nt2*16 + lr) * 32 + lg * 8];
#pragma unroll
    for (int mt = 0; mt < 4; mt++)
#pragma unroll
      for (int nt2 = 0; nt2 < 4; nt2++)
        acc[mt][nt2] = MFMA(af[mt], bf[nt2], acc[mt][nt2]);
    __syncthreads();                       // drains vmcnt(0)+lgkm, barrier
    cur ^= 1;
  }
#pragma unroll
  for (int mt = 0; mt < 4; mt++){
#pragma unroll
    for (int r = 0; r < 4; r++){
      int gr = row0 + wm + mt*16 + lg*4 + r;
#pragma unroll
      for (int nt2 = 0; nt2 < 4; nt2++){
        int gc = col0 + wn + nt2*16 + lr;
        float val = acc[mt][nt2][r] + bias[gc];
        if constexpr (EPI == 1){
          val = 0.5f * val * (1.f + erff(val * 0.70710678118f));
        }
        if constexpr (EPI == 2){
          float ov = val + res[(size_t)gr * N + gc];
          ((float*)Cout)[(size_t)gr * N + gc] = ov;
        } else {
          ((unsigned short*)Cout)[(size_t)gr * N + gc] = f2bf(val);
        }
      }
    }
  }
}

// ---------- RoPE in-place, NEGATED rotation (verified r8), strided rows ----------
template<int NH>
__global__ __launch_bounds__(256) void rope_k(unsigned short* base, int rs){
  int idx = blockIdx.x * 8 + (threadIdx.x >> 5);
  int d = threadIdx.x & 31;
  int row = idx / NH;          // b*T + t
  int head = idx % NH;
  int t = row & (TT - 1);
  unsigned short* p = base + (size_t)row * rs + head * HDW;
  float x1 = bf2f(p[d]);
  float x2 = bf2f(p[d + 32]);
  float theta = powf(10000.f, -(float)d * (1.f / 32.f));
  float c, s;
  sincosf((float)t * theta, &c, &s);
  p[d]      = f2bf(x1 * c + x2 * s);
  p[d + 32] = f2bf(x2 * c - x1 * s);
}

// ---------- V transpose: packed v rows (stride rs) -> vt[b][kvh][d][t] ----------
__global__ __launch_bounds__(256) void vtrans_k(const unsigned short* __restrict__ v, int rs,
                                                unsigned short* __restrict__ vt){
  __shared__ unsigned short tile[64][72];
  int t0 = blockIdx.x * 64;
  int kvh = blockIdx.y, b = blockIdx.z;
  int i = threadIdx.x;
  int tl = i >> 2, dc = (i & 3) * 16;
  const unsigned short* src = v + (size_t)(b * TT + t0 + tl) * rs + kvh * HDW + dc;
  *(uint4*)&tile[tl][dc]     = *(const uint4*)src;
  *(uint4*)&tile[tl][dc + 8] = *(const uint4*)(src + 8);
  __syncthreads();
  int d = i >> 2, tc = (i & 3) * 16;
  unsigned short tmp[16];
#pragma unroll
  for (int e = 0; e < 16; e++) tmp[e] = tile[tc + e][d];
  unsigned short* dst = vt + ((size_t)((b * KVHN + kvh) * HDW) + d) * TT + t0 + tc;
  *(uint4*)dst       = *(uint4*)tmp;
  *(uint4*)(dst + 8) = *(uint4*)(tmp + 8);
}

// ---------- flash attention, 1 wave per (b, h, 32-row q-tile); strided q/k ----------
__global__ __launch_bounds__(64) void attn_k(const unsigned short* __restrict__ q, int qrs,
                                             const unsigned short* __restrict__ k, int krs,
                                             const unsigned short* __restrict__ vt,
                                             unsigned short* __restrict__ o){
  __shared__ unsigned short P[32 * 40];
  __shared__ float sc_l[32];
  int qt = blockIdx.x, h = blockIdx.y, b = blockIdx.z;
  int kvh = h >> 2;
  int lane = threadIdx.x;
  int lr = lane & 15, lg = lane >> 4;
  int q0 = qt * 32;
  bf16x8 qf[2][2];
#pragma unroll
  for (int qi = 0; qi < 2; qi++)
#pragma unroll
    for (int ks = 0; ks < 2; ks++)
      qf[qi][ks] = *(const bf16x8*)(q + (size_t)(b*TT + q0 + qi*16 + lr) * qrs + h * HDW + ks*32 + lg*8);
  f32x4 oa[2][4] = {};
  float m_st[2] = {-1e30f, -1e30f};
  float l_st[2] = {0.f, 0.f};
  int kt_lo = (q0 - (WIN - 1)) > 0 ? ((q0 - (WIN - 1)) >> 5) : 0;
  int kt_hi = (q0 + 31) >> 5;
  for (int kt = kt_lo; kt <= kt_hi; kt++){
    int kb = kt * 32;
    bf16x8 kf[2][2];
#pragma unroll
    for (int ki = 0; ki < 2; ki++)
#pragma unroll
      for (int ks = 0; ks < 2; ks++)
        kf[ki][ks] = *(const bf16x8*)(k + (size_t)(b*TT + kb + ki*16 + lr) * krs + kvh * HDW + ks*32 + lg*8);
    f32x4 s[2][2] = {};
#pragma unroll
    for (int ki = 0; ki < 2; ki++)
#pragma unroll
      for (int qi = 0; qi < 2; qi++){
        s[ki][qi] = MFMA(kf[ki][0], qf[qi][0], s[ki][qi]);
        s[ki][qi] = MFMA(kf[ki][1], qf[qi][1], s[ki][qi]);
      }
#pragma unroll
    for (int qi = 0; qi < 2; qi++){
      int qa = q0 + qi*16 + lr;
      float pv[8];
      float mx = -1e30f;
#pragma unroll
      for (int ki = 0; ki < 2; ki++)
#pragma unroll
        for (int r = 0; r < 4; r++){
          int ka = kb + ki*16 + lg*4 + r;
          float val = s[ki][qi][r] * 0.125f;
          bool ok = (ka <= qa) && (qa - ka < WIN);
          val = ok ? val : -1e9f;
          pv[ki*4 + r] = val;
          mx = fmaxf(mx, val);
        }
      mx = fmaxf(mx, __shfl_xor(mx, 16));
      mx = fmaxf(mx, __shfl_xor(mx, 32));
      float mn = fmaxf(m_st[qi], mx);
      float scl = __expf(m_st[qi] - mn);
      m_st[qi] = mn;
      float ls = 0.f;
#pragma unroll
      for (int j = 0; j < 8; j++){ float p = __expf(pv[j] - mn); pv[j] = p; ls += p; }
      ls += __shfl_xor(ls, 16);
      ls += __shfl_xor(ls, 32);
      l_st[qi] = l_st[qi] * scl + ls;
#pragma unroll
      for (int ki = 0; ki < 2; ki++){
        uint2 w;
        w.x = (unsigned)f2bf(pv[ki*4+0]) | ((unsigned)f2bf(pv[ki*4+1]) << 16);
        w.y = (unsigned)f2bf(pv[ki*4+2]) | ((unsigned)f2bf(pv[ki*4+3]) << 16);
        *(uint2*)&P[(qi*16 + lr) * 40 + ki*16 + lg*4] = w;
      }
      if (lg == 0) sc_l[qi*16 + lr] = scl;
    }
    __syncthreads();
#pragma unroll
    for (int qi = 0; qi < 2; qi++)
#pragma unroll
      for (int r = 0; r < 4; r++){
        float f = sc_l[qi*16 + lg*4 + r];
#pragma unroll
        for (int di = 0; di < 4; di++) oa[qi][di][r] *= f;
      }
    bf16x8 pa[2];
#pragma unroll
    for (int qi = 0; qi < 2; qi++)
      pa[qi] = *(const bf16x8*)&P[(qi*16 + lr) * 40 + lg*8];
#pragma unroll
    for (int di = 0; di < 4; di++){
      bf16x8 vb = *(const bf16x8*)(vt + ((size_t)((b*KVHN + kvh) * HDW) + di*16 + lr) * TT + kb + lg*8);
#pragma unroll
      for (int qi = 0; qi < 2; qi++)
        oa[qi][di] = MFMA(pa[qi], vb, oa[qi][di]);
    }
    __syncthreads();
  }
  if (lg == 0){ sc_l[lr] = l_st[0]; sc_l[16 + lr] = l_st[1]; }
  __syncthreads();
#pragma unroll
  for (int qi = 0; qi < 2; qi++)
#pragma unroll
    for (int r = 0; r < 4; r++){
      float inv = 1.f / sc_l[qi*16 + lg*4 + r];
      int t = q0 + qi*16 + lg*4 + r;
#pragma unroll
      for (int di = 0; di < 4; di++)
        o[((size_t)((b*TT + t) * HH) + h) * HDW + di*16 + lr] = f2bf(oa[qi][di][r] * inv);
    }
}

extern "C" void kernel_launch(void* const* d_in, const int* in_sizes, int n_in,
                              void* d_out, int out_size, void* d_ws, size_t ws_size,
                              hipStream_t stream){
  const float* x   = (const float*)d_in[0];
  const float* Wq  = (const float*)d_in[1];
  const float* bq  = (const float*)d_in[2];
  const float* Wk  = (const float*)d_in[3];
  const float* bk  = (const float*)d_in[4];
  const float* Wv  = (const float*)d_in[5];
  const float* bv  = (const float*)d_in[6];
  const float* Wo  = (const float*)d_in[7];
  const float* bo  = (const float*)d_in[8];
  const float* g1  = (const float*)d_in[9];
  const float* b1  = (const float*)d_in[10];
  const float* Wf1 = (const float*)d_in[11];
  const float* bf1 = (const float*)d_in[12];
  const float* Wf2 = (const float*)d_in[13];
  const float* bf2 = (const float*)d_in[14];
  const float* g2  = (const float*)d_in[15];
  const float* b2  = (const float*)d_in[16];

  static const int want[17] = {4194304, 1048576, 1024, 262144, 256, 262144, 256,
                               1048576, 1024, 1024, 1024, 4194304, 4096, 4194304,
                               1024, 1024, 1024};
  bool bad = (n_in != 17) || (out_size != 4194304);
  if (!bad) for (int i = 0; i < 17; i++) if (in_sizes[i] != want[i]) bad = true;
  if (bad){
    zero_k<<<2048, 256, 0, stream>>>((float*)d_out, out_size);
    return;
  }

  const int M = 4 * TT;       // 4096 rows
  const int QKVN = 1536;      // packed q|k|v width
  char* ws = (char*)d_ws;
  size_t off = 0;
  auto alloc = [&](size_t bytes) -> void* {
    void* p = ws + off; off += (bytes + 255) & ~(size_t)255; return p;
  };
  unsigned short* wqkv = (unsigned short*)alloc((size_t)QKVN * DD * 2);
  unsigned short* wto  = (unsigned short*)alloc((size_t)DD * DD * 2);
  unsigned short* wtf1 = (unsigned short*)alloc((size_t)DFFN * DD * 2);
  unsigned short* wtf2 = (unsigned short*)alloc((size_t)DD * DFFN * 2);
  float*          bqkv = (float*)alloc((size_t)QKVN * 4);
  unsigned short* h1   = (unsigned short*)alloc((size_t)M * DD * 2);
  unsigned short* qkv  = (unsigned short*)alloc((size_t)M * QKVN * 2);
  unsigned short* vtb  = (unsigned short*)alloc((size_t)M * 256 * 2);
  unsigned short* ao   = (unsigned short*)alloc((size_t)M * DD * 2);
  float*          x2   = (float*)alloc((size_t)M * DD * 4);
  unsigned short* h2   = h1;            // reuse
  unsigned short* ff   = (unsigned short*)alloc((size_t)M * DFFN * 2);
  (void)ws_size;

  // weights -> bf16 transposed (QKV packed: rows 0-1023 Wq, 1024-1279 Wk, 1280-1535 Wv)
  wtrans_k<<<dim3(DD/32,  DD/32),  256, 0, stream>>>(Wq,  wqkv,                       DD,  DD);
  wtrans_k<<<dim3(256/32, DD/32),  256, 0, stream>>>(Wk,  wqkv + (size_t)1024 * DD,   DD,  256);
  wtrans_k<<<dim3(256/32, DD/32),  256, 0, stream>>>(Wv,  wqkv + (size_t)1280 * DD,   DD,  256);
  wtrans_k<<<dim3(DD/32,  DD/32),  256, 0, stream>>>(Wo,  wto,  DD,  DD);
  wtrans_k<<<dim3(DFFN/32,DD/32),  256, 0, stream>>>(Wf1, wtf1, DD,  DFFN);
  wtrans_k<<<dim3(DD/32,  DFFN/32),256, 0, stream>>>(Wf2, wtf2, DFFN,DD);
  packb_k<<<6, 256, 0, stream>>>(bq, bk, bv, bqkv);

  // LN1
  ln_k<<<M, 256, 0, stream>>>(x, g1, b1, h1);

  // QKV fused (N=1536)
  gemm_k<0><<<dim3(M/128, QKVN/128), 256, 0, stream>>>(h1, wqkv, bqkv, nullptr, qkv, M, QKVN, DD);

  // RoPE (negated rotation, verified r8) on packed buffer
  rope_k<HH>  <<<(M * HH) / 8,   256, 0, stream>>>(qkv,        QKVN);
  rope_k<KVHN><<<(M * KVHN) / 8, 256, 0, stream>>>(qkv + 1024, QKVN);

  // V transpose (from packed, stride 1536)
  vtrans_k<<<dim3(TT/64, KVHN, 4), 256, 0, stream>>>(qkv + 1280, QKVN, vtb);

  // attention (MFMA flash, strided q/k)
  attn_k<<<dim3(TT/32, HH, 4), 64, 0, stream>>>(qkv, QKVN, qkv + 1024, QKVN, vtb, ao);

  // Wo + residual (fp32 out)
  gemm_k<2><<<dim3(M/128, DD/128), 256, 0, stream>>>(ao, wto, bo, x, x2, M, DD, DD);

  // LN2
  ln_k<<<M, 256, 0, stream>>>(x2, g2, b2, h2);

  // FFN
  gemm_k<1><<<dim3(M/128, DFFN/128), 256, 0, stream>>>(h2, wtf1, bf1, nullptr, ff, M, DFFN, DD);
  gemm_k<2><<<dim3(M/128, DD/128),   256, 0, stream>>>(ff, wtf2, bf2, x2, (float*)d_out, M, DD, DFFN);
}

// Round 12
// 249.079 us; speedup vs baseline: 12.1815x; 1.1553x over previous
//
#include <hip/hip_runtime.h>
#include <hip/hip_bf16.h>
#include <math.h>

#define TT 1024
#define DD 1024
#define HH 16
#define KVHN 4
#define HDW 64
#define DFFN 4096
#define WIN 256

typedef __attribute__((ext_vector_type(4))) float f32x4;
typedef __attribute__((ext_vector_type(8))) __bf16 bf16x8;

typedef const __attribute__((address_space(1))) void gas_t;
typedef __attribute__((address_space(3))) void las_t;

__device__ inline unsigned short f2bf(float f){
  union { float f; unsigned u; } x; x.f = f;
  unsigned r = x.u + 0x7fffu + ((x.u >> 16) & 1u);
  return (unsigned short)(r >> 16);
}
__device__ inline float bf2f(unsigned short b){
  union { unsigned u; float f; } x; x.u = ((unsigned)b) << 16; return x.f;
}
__device__ inline f32x4 MFMA(bf16x8 a, bf16x8 b, f32x4 c){
  return __builtin_amdgcn_mfma_f32_16x16x32_bf16(a, b, c, 0, 0, 0);
}

__global__ void zero_k(float* out, int n){
  for (int i = blockIdx.x * blockDim.x + threadIdx.x; i < n; i += gridDim.x * blockDim.x)
    out[i] = 0.f;
}

// ---------- weight transpose: W[K][N] fp32 -> Wt[N][K] bf16 ----------
__global__ __launch_bounds__(256) void wtrans_k(const float* __restrict__ W,
                                                unsigned short* __restrict__ Wt,
                                                int K, int N){
  __shared__ float t[32][33];
  int n0 = blockIdx.x * 32, k0 = blockIdx.y * 32;
  int tx = threadIdx.x & 31, ty = threadIdx.x >> 5;
#pragma unroll
  for (int i = 0; i < 4; i++){
    int kk = ty * 4 + i;
    t[kk][tx] = W[(size_t)(k0 + kk) * N + n0 + tx];
  }
  __syncthreads();
#pragma unroll
  for (int i = 0; i < 4; i++){
    int nn = ty * 4 + i;
    Wt[(size_t)(n0 + nn) * K + k0 + tx] = f2bf(t[tx][nn]);
  }
}

// ---------- pack QKV bias ----------
__global__ void packb_k(const float* bq, const float* bk, const float* bv, float* o){
  int i = blockIdx.x * 256 + threadIdx.x;
  if (i < 1536)
    o[i] = (i < 1024) ? bq[i] : ((i < 1280) ? bk[i - 1024] : bv[i - 1280]);
}

// ---------- layernorm: fp32 row -> bf16 row ----------
__global__ __launch_bounds__(256) void ln_k(const float* __restrict__ x,
                                            const float* __restrict__ g,
                                            const float* __restrict__ b,
                                            unsigned short* __restrict__ out){
  __shared__ float red[4];
  int row = blockIdx.x, tid = threadIdx.x;
  const float* xr = x + (size_t)row * DD;
  float4 v = *(const float4*)(xr + tid * 4);
  float s = v.x + v.y + v.z + v.w;
#pragma unroll
  for (int off = 32; off; off >>= 1) s += __shfl_xor(s, off);
  if ((tid & 63) == 0) red[tid >> 6] = s;
  __syncthreads();
  float mu = (red[0] + red[1] + red[2] + red[3]) * (1.f / DD);
  __syncthreads();
  float dx = v.x - mu, dy = v.y - mu, dz = v.z - mu, dw = v.w - mu;
  float sq = dx*dx + dy*dy + dz*dz + dw*dw;
#pragma unroll
  for (int off = 32; off; off >>= 1) sq += __shfl_xor(sq, off);
  if ((tid & 63) == 0) red[tid >> 6] = sq;
  __syncthreads();
  float var = (red[0] + red[1] + red[2] + red[3]) * (1.f / DD);
  float inv = rsqrtf(var + 1e-5f);
  float4 gv = *(const float4*)(g + tid * 4);
  float4 bv = *(const float4*)(b + tid * 4);
  unsigned short* orow = out + (size_t)row * DD + tid * 4;
  orow[0] = f2bf(dx * inv * gv.x + bv.x);
  orow[1] = f2bf(dy * inv * gv.y + bv.y);
  orow[2] = f2bf(dz * inv * gv.z + bv.z);
  orow[3] = f2bf(dw * inv * gv.w + bv.w);
}

// ---------- bf16 MFMA GEMM: BK=64 dbuf + global_load_lds + T2 source-swizzle ----------
// LDS layout: row-major [128][64] with byte ^= ((row&7)<<4) XOR swizzle.
// gload_lds writes linearly => per-lane SOURCE permuted: lane l stages
// row w*8+(l>>3), chunk (l&7)^(l>>3). Read applies the same XOR.
// C = A[M][K] @ Bt[N][K]^T + bias. EPI 0: bf16. 1: GELU bf16. 2: +res fp32.
template<int EPI>
__global__ __launch_bounds__(256) void gemm_k(const unsigned short* __restrict__ A,
                                              const unsigned short* __restrict__ Bt,
                                              const float* __restrict__ bias,
                                              const float* __restrict__ res,
                                              void* __restrict__ Cout,
                                              int M, int N, int K){
  __shared__ unsigned short As[2][128 * 64];
  __shared__ unsigned short Bs[2][128 * 64];
  int tid = threadIdx.x;
  int row0 = blockIdx.x * 128, col0 = blockIdx.y * 128;
  int wid = tid >> 6, lane = tid & 63;
  int wm = (wid >> 1) * 64, wn = (wid & 1) * 64;
  int lr = lane & 15, lg = lane >> 4;
  f32x4 acc[4][4] = {};

  // staging source (pre-swizzled for linear LDS dest)
  int srow = wid * 8 + (lane >> 3);
  int scol = ((lane & 7) ^ (lane >> 3)) * 8;
  const unsigned short* gA0 = A  + (size_t)(row0 + srow) * K + scol;
  const unsigned short* gB0 = Bt + (size_t)(col0 + srow) * K + scol;
  int lbase = wid * 512;   // ushorts: wave-uniform LDS base (+ j*2048)

  int NT = K >> 6;
  // prologue: stage tile 0 -> buf 0
#pragma unroll
  for (int j = 0; j < 4; j++){
    __builtin_amdgcn_global_load_lds((gas_t*)(gA0 + (size_t)(j*32)*K), (las_t*)&As[0][j*2048 + lbase], 16, 0, 0);
    __builtin_amdgcn_global_load_lds((gas_t*)(gB0 + (size_t)(j*32)*K), (las_t*)&Bs[0][j*2048 + lbase], 16, 0, 0);
  }
  __syncthreads();
  int cur = 0;
  int xr8 = (lr & 7) << 3;   // read-side XOR (ushort units)
  for (int t = 0; t < NT; t++){
    if (t + 1 < NT){
      int k0 = (t + 1) << 6;
      int nb = cur ^ 1;
#pragma unroll
      for (int j = 0; j < 4; j++){
        __builtin_amdgcn_global_load_lds((gas_t*)(gA0 + (size_t)(j*32)*K + k0), (las_t*)&As[nb][j*2048 + lbase], 16, 0, 0);
        __builtin_amdgcn_global_load_lds((gas_t*)(gB0 + (size_t)(j*32)*K + k0), (las_t*)&Bs[nb][j*2048 + lbase], 16, 0, 0);
      }
    }
#pragma unroll
    for (int kk = 0; kk < 2; kk++){
      int xk = (kk*32 + lg*8) ^ xr8;
      bf16x8 af[4], bf[4];
#pragma unroll
      for (int mt = 0; mt < 4; mt++)
        af[mt] = *(const bf16x8*)&As[cur][(wm + mt*16 + lr) * 64 + xk];
#pragma unroll
      for (int nt2 = 0; nt2 < 4; nt2++)
        bf[nt2] = *(const bf16x8*)&Bs[cur][(wn + nt2*16 + lr) * 64 + xk];
#pragma unroll
      for (int mt = 0; mt < 4; mt++)
#pragma unroll
        for (int nt2 = 0; nt2 < 4; nt2++)
          acc[mt][nt2] = MFMA(af[mt], bf[nt2], acc[mt][nt2]);
    }
    __syncthreads();
    cur ^= 1;
  }
#pragma unroll
  for (int mt = 0; mt < 4; mt++){
#pragma unroll
    for (int r = 0; r < 4; r++){
      int gr = row0 + wm + mt*16 + lg*4 + r;
#pragma unroll
      for (int nt2 = 0; nt2 < 4; nt2++){
        int gc = col0 + wn + nt2*16 + lr;
        float val = acc[mt][nt2][r] + bias[gc];
        if constexpr (EPI == 1){
          val = 0.5f * val * (1.f + erff(val * 0.70710678118f));
        }
        if constexpr (EPI == 2){
          float ov = val + res[(size_t)gr * N + gc];
          ((float*)Cout)[(size_t)gr * N + gc] = ov;
        } else {
          ((unsigned short*)Cout)[(size_t)gr * N + gc] = f2bf(val);
        }
      }
    }
  }
}

// ---------- RoPE in-place, NEGATED rotation (verified r8), strided rows ----------
template<int NH>
__global__ __launch_bounds__(256) void rope_k(unsigned short* base, int rs){
  int idx = blockIdx.x * 8 + (threadIdx.x >> 5);
  int d = threadIdx.x & 31;
  int row = idx / NH;          // b*T + t
  int head = idx % NH;
  int t = row & (TT - 1);
  unsigned short* p = base + (size_t)row * rs + head * HDW;
  float x1 = bf2f(p[d]);
  float x2 = bf2f(p[d + 32]);
  float theta = powf(10000.f, -(float)d * (1.f / 32.f));
  float c, s;
  sincosf((float)t * theta, &c, &s);
  p[d]      = f2bf(x1 * c + x2 * s);
  p[d + 32] = f2bf(x2 * c - x1 * s);
}

// ---------- V transpose: packed v rows (stride rs) -> vt[b][kvh][d][t] ----------
__global__ __launch_bounds__(256) void vtrans_k(const unsigned short* __restrict__ v, int rs,
                                                unsigned short* __restrict__ vt){
  __shared__ unsigned short tile[64][72];
  int t0 = blockIdx.x * 64;
  int kvh = blockIdx.y, b = blockIdx.z;
  int i = threadIdx.x;
  int tl = i >> 2, dc = (i & 3) * 16;
  const unsigned short* src = v + (size_t)(b * TT + t0 + tl) * rs + kvh * HDW + dc;
  *(uint4*)&tile[tl][dc]     = *(const uint4*)src;
  *(uint4*)&tile[tl][dc + 8] = *(const uint4*)(src + 8);
  __syncthreads();
  int d = i >> 2, tc = (i & 3) * 16;
  unsigned short tmp[16];
#pragma unroll
  for (int e = 0; e < 16; e++) tmp[e] = tile[tc + e][d];
  unsigned short* dst = vt + ((size_t)((b * KVHN + kvh) * HDW) + d) * TT + t0 + tc;
  *(uint4*)dst       = *(uint4*)tmp;
  *(uint4*)(dst + 8) = *(uint4*)(tmp + 8);
}

// ---------- flash attention, 1 wave per (b, h, 32-row q-tile); strided q/k ----------
__global__ __launch_bounds__(64) void attn_k(const unsigned short* __restrict__ q, int qrs,
                                             const unsigned short* __restrict__ k, int krs,
                                             const unsigned short* __restrict__ vt,
                                             unsigned short* __restrict__ o){
  __shared__ unsigned short P[32 * 40];
  __shared__ float sc_l[32];
  int qt = blockIdx.x, h = blockIdx.y, b = blockIdx.z;
  int kvh = h >> 2;
  int lane = threadIdx.x;
  int lr = lane & 15, lg = lane >> 4;
  int q0 = qt * 32;
  bf16x8 qf[2][2];
#pragma unroll
  for (int qi = 0; qi < 2; qi++)
#pragma unroll
    for (int ks = 0; ks < 2; ks++)
      qf[qi][ks] = *(const bf16x8*)(q + (size_t)(b*TT + q0 + qi*16 + lr) * qrs + h * HDW + ks*32 + lg*8);
  f32x4 oa[2][4] = {};
  float m_st[2] = {-1e30f, -1e30f};
  float l_st[2] = {0.f, 0.f};
  int kt_lo = (q0 - (WIN - 1)) > 0 ? ((q0 - (WIN - 1)) >> 5) : 0;
  int kt_hi = (q0 + 31) >> 5;
  for (int kt = kt_lo; kt <= kt_hi; kt++){
    int kb = kt * 32;
    bf16x8 kf[2][2];
#pragma unroll
    for (int ki = 0; ki < 2; ki++)
#pragma unroll
      for (int ks = 0; ks < 2; ks++)
        kf[ki][ks] = *(const bf16x8*)(k + (size_t)(b*TT + kb + ki*16 + lr) * krs + kvh * HDW + ks*32 + lg*8);
    f32x4 s[2][2] = {};
#pragma unroll
    for (int ki = 0; ki < 2; ki++)
#pragma unroll
      for (int qi = 0; qi < 2; qi++){
        s[ki][qi] = MFMA(kf[ki][0], qf[qi][0], s[ki][qi]);
        s[ki][qi] = MFMA(kf[ki][1], qf[qi][1], s[ki][qi]);
      }
#pragma unroll
    for (int qi = 0; qi < 2; qi++){
      int qa = q0 + qi*16 + lr;
      float pv[8];
      float mx = -1e30f;
#pragma unroll
      for (int ki = 0; ki < 2; ki++)
#pragma unroll
        for (int r = 0; r < 4; r++){
          int ka = kb + ki*16 + lg*4 + r;
          float val = s[ki][qi][r] * 0.125f;
          bool ok = (ka <= qa) && (qa - ka < WIN);
          val = ok ? val : -1e9f;
          pv[ki*4 + r] = val;
          mx = fmaxf(mx, val);
        }
      mx = fmaxf(mx, __shfl_xor(mx, 16));
      mx = fmaxf(mx, __shfl_xor(mx, 32));
      float mn = fmaxf(m_st[qi], mx);
      float scl = __expf(m_st[qi] - mn);
      m_st[qi] = mn;
      float ls = 0.f;
#pragma unroll
      for (int j = 0; j < 8; j++){ float p = __expf(pv[j] - mn); pv[j] = p; ls += p; }
      ls += __shfl_xor(ls, 16);
      ls += __shfl_xor(ls, 32);
      l_st[qi] = l_st[qi] * scl + ls;
#pragma unroll
      for (int ki = 0; ki < 2; ki++){
        uint2 w;
        w.x = (unsigned)f2bf(pv[ki*4+0]) | ((unsigned)f2bf(pv[ki*4+1]) << 16);
        w.y = (unsigned)f2bf(pv[ki*4+2]) | ((unsigned)f2bf(pv[ki*4+3]) << 16);
        *(uint2*)&P[(qi*16 + lr) * 40 + ki*16 + lg*4] = w;
      }
      if (lg == 0) sc_l[qi*16 + lr] = scl;
    }
    __syncthreads();
#pragma unroll
    for (int qi = 0; qi < 2; qi++)
#pragma unroll
      for (int r = 0; r < 4; r++){
        float f = sc_l[qi*16 + lg*4 + r];
#pragma unroll
        for (int di = 0; di < 4; di++) oa[qi][di][r] *= f;
      }
    bf16x8 pa[2];
#pragma unroll
    for (int qi = 0; qi < 2; qi++)
      pa[qi] = *(const bf16x8*)&P[(qi*16 + lr) * 40 + lg*8];
#pragma unroll
    for (int di = 0; di < 4; di++){
      bf16x8 vb = *(const bf16x8*)(vt + ((size_t)((b*KVHN + kvh) * HDW) + di*16 + lr) * TT + kb + lg*8);
#pragma unroll
      for (int qi = 0; qi < 2; qi++)
        oa[qi][di] = MFMA(pa[qi], vb, oa[qi][di]);
    }
    __syncthreads();
  }
  if (lg == 0){ sc_l[lr] = l_st[0]; sc_l[16 + lr] = l_st[1]; }
  __syncthreads();
#pragma unroll
  for (int qi = 0; qi < 2; qi++)
#pragma unroll
    for (int r = 0; r < 4; r++){
      float inv = 1.f / sc_l[qi*16 + lg*4 + r];
      int t = q0 + qi*16 + lg*4 + r;
#pragma unroll
      for (int di = 0; di < 4; di++)
        o[((size_t)((b*TT + t) * HH) + h) * HDW + di*16 + lr] = f2bf(oa[qi][di][r] * inv);
    }
}

extern "C" void kernel_launch(void* const* d_in, const int* in_sizes, int n_in,
                              void* d_out, int out_size, void* d_ws, size_t ws_size,
                              hipStream_t stream){
  const float* x   = (const float*)d_in[0];
  const float* Wq  = (const float*)d_in[1];
  const float* bq  = (const float*)d_in[2];
  const float* Wk  = (const float*)d_in[3];
  const float* bk  = (const float*)d_in[4];
  const float* Wv  = (const float*)d_in[5];
  const float* bv  = (const float*)d_in[6];
  const float* Wo  = (const float*)d_in[7];
  const float* bo  = (const float*)d_in[8];
  const float* g1  = (const float*)d_in[9];
  const float* b1  = (const float*)d_in[10];
  const float* Wf1 = (const float*)d_in[11];
  const float* bf1 = (const float*)d_in[12];
  const float* Wf2 = (const float*)d_in[13];
  const float* bf2 = (const float*)d_in[14];
  const float* g2  = (const float*)d_in[15];
  const float* b2  = (const float*)d_in[16];

  static const int want[17] = {4194304, 1048576, 1024, 262144, 256, 262144, 256,
                               1048576, 1024, 1024, 1024, 4194304, 4096, 4194304,
                               1024, 1024, 1024};
  bool bad = (n_in != 17) || (out_size != 4194304);
  if (!bad) for (int i = 0; i < 17; i++) if (in_sizes[i] != want[i]) bad = true;
  if (bad){
    zero_k<<<2048, 256, 0, stream>>>((float*)d_out, out_size);
    return;
  }

  const int M = 4 * TT;       // 4096 rows
  const int QKVN = 1536;      // packed q|k|v width
  char* ws = (char*)d_ws;
  size_t off = 0;
  auto alloc = [&](size_t bytes) -> void* {
    void* p = ws + off; off += (bytes + 255) & ~(size_t)255; return p;
  };
  unsigned short* wqkv = (unsigned short*)alloc((size_t)QKVN * DD * 2);
  unsigned short* wto  = (unsigned short*)alloc((size_t)DD * DD * 2);
  unsigned short* wtf1 = (unsigned short*)alloc((size_t)DFFN * DD * 2);
  unsigned short* wtf2 = (unsigned short*)alloc((size_t)DD * DFFN * 2);
  float*          bqkv = (float*)alloc((size_t)QKVN * 4);
  unsigned short* h1   = (unsigned short*)alloc((size_t)M * DD * 2);
  unsigned short* qkv  = (unsigned short*)alloc((size_t)M * QKVN * 2);
  unsigned short* vtb  = (unsigned short*)alloc((size_t)M * 256 * 2);
  unsigned short* ao   = (unsigned short*)alloc((size_t)M * DD * 2);
  float*          x2   = (float*)alloc((size_t)M * DD * 4);
  unsigned short* h2   = h1;            // reuse
  unsigned short* ff   = (unsigned short*)alloc((size_t)M * DFFN * 2);
  (void)ws_size;

  // weights -> bf16 transposed (QKV packed: rows 0-1023 Wq, 1024-1279 Wk, 1280-1535 Wv)
  wtrans_k<<<dim3(DD/32,  DD/32),  256, 0, stream>>>(Wq,  wqkv,                       DD,  DD);
  wtrans_k<<<dim3(256/32, DD/32),  256, 0, stream>>>(Wk,  wqkv + (size_t)1024 * DD,   DD,  256);
  wtrans_k<<<dim3(256/32, DD/32),  256, 0, stream>>>(Wv,  wqkv + (size_t)1280 * DD,   DD,  256);
  wtrans_k<<<dim3(DD/32,  DD/32),  256, 0, stream>>>(Wo,  wto,  DD,  DD);
  wtrans_k<<<dim3(DFFN/32,DD/32),  256, 0, stream>>>(Wf1, wtf1, DD,  DFFN);
  wtrans_k<<<dim3(DD/32,  DFFN/32),256, 0, stream>>>(Wf2, wtf2, DFFN,DD);
  packb_k<<<6, 256, 0, stream>>>(bq, bk, bv, bqkv);

  // LN1
  ln_k<<<M, 256, 0, stream>>>(x, g1, b1, h1);

  // QKV fused (N=1536)
  gemm_k<0><<<dim3(M/128, QKVN/128), 256, 0, stream>>>(h1, wqkv, bqkv, nullptr, qkv, M, QKVN, DD);

  // RoPE (negated rotation, verified r8) on packed buffer
  rope_k<HH>  <<<(M * HH) / 8,   256, 0, stream>>>(qkv,        QKVN);
  rope_k<KVHN><<<(M * KVHN) / 8, 256, 0, stream>>>(qkv + 1024, QKVN);

  // V transpose (from packed, stride 1536)
  vtrans_k<<<dim3(TT/64, KVHN, 4), 256, 0, stream>>>(qkv + 1280, QKVN, vtb);

  // attention (MFMA flash, strided q/k)
  attn_k<<<dim3(TT/32, HH, 4), 64, 0, stream>>>(qkv, QKVN, qkv + 1024, QKVN, vtb, ao);

  // Wo + residual (fp32 out)
  gemm_k<2><<<dim3(M/128, DD/128), 256, 0, stream>>>(ao, wto, bo, x, x2, M, DD, DD);

  // LN2
  ln_k<<<M, 256, 0, stream>>>(x2, g2, b2, h2);

  // FFN
  gemm_k<1><<<dim3(M/128, DFFN/128), 256, 0, stream>>>(h2, wtf1, bf1, nullptr, ff, M, DFFN, DD);
  gemm_k<2><<<dim3(M/128, DD/128),   256, 0, stream>>>(ff, wtf2, bf2, x2, (float*)d_out, M, DD, DFFN);
}